// Round 6
// baseline (273.534 us; speedup 1.0000x reference)
//
#include <hip/hip_runtime.h>

// MultiScaleRoIAlign: B=2, Nb=256 (R=512 rois), C=256, PH=PW=7, GRID=2.
// R10: structural ablation. R4/R5/R6/R9 (four different LDS-staging
// schedules, incl. a verified-installed double-buffered counted-vmcnt
// pipeline) ALL land at 69-77us -> the staging round-trip itself is the
// invariant, and the per-roi patch (~256KB all-channels) fits L2 (guide
// Common-mistake #7: staging L2-fit data is pure overhead).
// Global-direct: lane = bin, wave = 16-channel strip, block = (roi,
// channel-quarter), grid 2048 XCD-swizzled (quarters of a roi co-located
// per XCD L2). Each lane precomputes 16 absolute tap offsets + weights
// ONCE (channel-invariant: channel stride = HW), then per channel does
// 16 independent L1/L2 gathers + 16 FMA + 1 coalesced store.
// No LDS. No barriers. No shuffles. No patch-bounds math.

#define PHW 49

__global__ __launch_bounds__(256) void msroi_kernel(
    const float* __restrict__ f0, const float* __restrict__ f1,
    const float* __restrict__ f2, const float* __restrict__ f3,
    const float* __restrict__ boxes, float* __restrict__ out)
{
    const int C = 256, Nb = 256;

    // XCD-aware swizzle (nwg=2048, nwg%8==0 -> simple bijective form):
    // consecutive swizzled ids stay on one XCD; quarters of a roi adjacent.
    const int nwg = gridDim.x;                   // 2048
    const int cpx = nwg >> 3;                    // 256 per XCD
    const int orig = blockIdx.x;
    const int wgid = (orig & 7) * cpx + (orig >> 3);
    const int r = wgid >> 2;                     // roi 0..511
    const int quarter = wgid & 3;                // channel quarter 0..3

    const int tid = threadIdx.x;                 // 0..255
    const int w = tid >> 6;                      // wave 0..3
    const int lane = tid & 63;
    const int b = r / Nb;

    // ---- per-roi params (uniform) ----
    const float x1b = boxes[r * 4 + 0];
    const float y1b = boxes[r * 4 + 1];
    const float x2b = boxes[r * 4 + 2];
    const float y2b = boxes[r * 4 + 3];
    const float area = fmaxf((x2b - x1b) * (y2b - y1b), 0.0f);
    const float s = sqrtf(area);
    float lv = floorf(4.0f + log2f(s / 224.0f + 1e-6f));
    lv = fminf(fmaxf(lv, 2.0f), 5.0f);
    const int lvl = (int)lv - 2;

    const float* feat;
    int H, W;
    float scale;
    switch (lvl) {
        case 0:  feat = f0; H = 200; W = 200; scale = 0.25f;    break;
        case 1:  feat = f1; H = 100; W = 100; scale = 0.125f;   break;
        case 2:  feat = f2; H = 50;  W = 50;  scale = 0.0625f;  break;
        default: feat = f3; H = 25;  W = 25;  scale = 0.03125f; break;
    }
    const int HW = H * W;

    const float x1 = x1b * scale, y1 = y1b * scale;
    const float x2 = x2b * scale, y2 = y2b * scale;
    const float roi_w = fmaxf(x2 - x1, 1.0f);
    const float roi_h = fmaxf(y2 - y1, 1.0f);
    const float bin_w = roi_w * (1.0f / 7.0f);
    const float bin_h = roi_h * (1.0f / 7.0f);

    // ---- per-lane bin: 16 absolute tap offsets + weights (channel-inv) ----
    const int bin = lane;                        // active if < 49
    const bool active = bin < PHW;
    int   goff[16];
    float wts[16];
    {
        const int bb = active ? bin : 0;
        const int ph = bb / 7;
        const int pw = bb - ph * 7;
#pragma unroll
        for (int g = 0; g < 4; ++g) {            // sample q = g (2x2 grid)
            const int iy = g >> 1, ix = g & 1;
            const float gy = (float)ph + ((float)iy + 0.5f) * 0.5f;
            const float gx = (float)pw + ((float)ix + 0.5f) * 0.5f;
            const float y = y1 + gy * bin_h;
            const float x = x1 + gx * bin_w;
            const bool valid = (y >= -1.0f) && (y <= (float)H) &&
                               (x >= -1.0f) && (x <= (float)W);
            const float yc = fminf(fmaxf(y, 0.0f), (float)(H - 1));
            const float xc = fminf(fmaxf(x, 0.0f), (float)(W - 1));
            const int yl = (int)floorf(yc);
            const int xl = (int)floorf(xc);
            const int yh = min(yl + 1, H - 1);
            const int xh = min(xl + 1, W - 1);
            const float ly = yc - (float)yl;
            const float lx = xc - (float)xl;
            const float hy = 1.0f - ly, hx = 1.0f - lx;
            const float m = valid ? 0.25f : 0.0f;
            goff[g * 4 + 0] = yl * W + xl;  wts[g * 4 + 0] = hy * hx * m;
            goff[g * 4 + 1] = yl * W + xh;  wts[g * 4 + 1] = hy * lx * m;
            goff[g * 4 + 2] = yh * W + xl;  wts[g * 4 + 2] = ly * hx * m;
            goff[g * 4 + 3] = yh * W + xh;  wts[g * 4 + 3] = ly * lx * m;
        }
    }

    // ---- channel strip: wave w of quarter q -> channels c0 .. c0+15 ----
    const int c0 = quarter * 64 + w * 16;
    const float* __restrict__ fpl = feat + (size_t)(b * C + c0) * HW;
    float* __restrict__ op = out + (size_t)r * C * PHW
                                 + (size_t)c0 * PHW + bin;

    if (active) {
#pragma unroll 2
        for (int cc = 0; cc < 16; ++cc) {
            const float* __restrict__ p = fpl + (size_t)cc * HW;
            float acc = 0.0f;
#pragma unroll
            for (int j = 0; j < 16; ++j)
                acc += wts[j] * p[goff[j]];      // independent L1/L2 gathers
            op[(size_t)cc * PHW] = acc;          // lanes -> consecutive dwords
        }
    }
}

extern "C" void kernel_launch(void* const* d_in, const int* in_sizes, int n_in,
                              void* d_out, int out_size, void* d_ws, size_t ws_size,
                              hipStream_t stream) {
    const float* f0 = (const float*)d_in[0];
    const float* f1 = (const float*)d_in[1];
    const float* f2 = (const float*)d_in[2];
    const float* f3 = (const float*)d_in[3];
    const float* boxes = (const float*)d_in[4];
    float* out = (float*)d_out;

    const int R = in_sizes[4] / 4;   // 512 rois
    dim3 grid(R * 4);                // (roi, channel-quarter), XCD-swizzled
    msroi_kernel<<<grid, 256, 0, stream>>>(f0, f1, f2, f3, boxes, out);
}

// Round 7
// 183.969 us; speedup vs baseline: 1.4868x; 1.4868x over previous
//
#include <hip/hip_runtime.h>

// MultiScaleRoIAlign: B=2, Nb=256 (R=512 rois), C=256, PH=PW=7, GRID=2.
// R11: DMA staging. R10 proved LDS staging is structurally required (global
// divergent gathers = ~50cy/wave-instr, 2.4x worse). R9's budget closes as
// VMEM(57k) + DS(49k) + VALU(38k) cy/CU in lockstep -> no single pipe, the
// SUM is the 70us plateau. global_load_lds deletes two budget lines:
//   - staging via DMA (no VGPR round-trip, no ds_writes, no lgkm)
//   - adaptive smax without register buffers (immune to R8's collapse:
//     DMA has no dest regs, so branchy issue can't be serialized-on-use)
//   - m173 pre-swizzled SOURCE: DMA dest is linear (base+lane*4), so lane's
//     global src = (elem s>>2, channel s&3) lands the channel-interleaved
//     float4 slab directly. Compute = R6's verified b128 quad-split.
// psize <= ~840 (derived: s*scale < 28 => patch <= ~29x29), so 4*psize
// <= 3360 => smax <= 14 < 15 batches of 256 slots.

#define PHW 49
#define NCHUNK 8
#define CH 32             // channels per block (8 rounds of 4)
#define SLABQ 960         // float4 per slab (3840 floats = 15360 B)

__global__ __launch_bounds__(256) void msroi_kernel(
    const float* __restrict__ f0, const float* __restrict__ f1,
    const float* __restrict__ f2, const float* __restrict__ f3,
    const float* __restrict__ boxes, float* __restrict__ out)
{
    const int C = 256, Nb = 256;
    const int r = blockIdx.x;            // roi 0..511
    const int chunk = blockIdx.y;        // 0..7
    const int tid = threadIdx.x;         // 0..255
    const int b = r / Nb;

    const int bin = tid >> 2;            // 0..63 (active if < 49)
    const int q   = tid & 3;             // 2x2 sample index within bin
    const bool active = bin < PHW;

    // ---- per-roi params (uniform) ----
    const float x1b = boxes[r * 4 + 0];
    const float y1b = boxes[r * 4 + 1];
    const float x2b = boxes[r * 4 + 2];
    const float y2b = boxes[r * 4 + 3];
    const float area = fmaxf((x2b - x1b) * (y2b - y1b), 0.0f);
    const float s = sqrtf(area);
    float lv = floorf(4.0f + log2f(s / 224.0f + 1e-6f));
    lv = fminf(fmaxf(lv, 2.0f), 5.0f);
    const int lvl = (int)lv - 2;

    const float* feat;
    int H, W;
    float scale;
    switch (lvl) {
        case 0:  feat = f0; H = 200; W = 200; scale = 0.25f;    break;
        case 1:  feat = f1; H = 100; W = 100; scale = 0.125f;   break;
        case 2:  feat = f2; H = 50;  W = 50;  scale = 0.0625f;  break;
        default: feat = f3; H = 25;  W = 25;  scale = 0.03125f; break;
    }
    const int HW = H * W;

    const float x1 = x1b * scale, y1 = y1b * scale;
    const float x2 = x2b * scale, y2 = y2b * scale;
    const float roi_w = fmaxf(x2 - x1, 1.0f);
    const float roi_h = fmaxf(y2 - y1, 1.0f);
    const float bin_w = roi_w * (1.0f / 7.0f);
    const float bin_h = roi_h * (1.0f / 7.0f);

    // ---- patch bounds (uniform) ----
    const float ys0 = fminf(fmaxf(y1 + 0.25f * bin_h, 0.0f), (float)(H - 1));
    const float ys1 = fminf(fmaxf(y1 + 6.75f * bin_h, 0.0f), (float)(H - 1));
    const float xs0 = fminf(fmaxf(x1 + 0.25f * bin_w, 0.0f), (float)(W - 1));
    const float xs1 = fminf(fmaxf(x1 + 6.75f * bin_w, 0.0f), (float)(W - 1));
    const int row0 = (int)floorf(ys0);
    const int row1 = min((int)floorf(ys1) + 1, H - 1);
    const int col0 = (int)floorf(xs0);
    const int col1 = min((int)floorf(xs1) + 1, W - 1);
    const int prows = row1 - row0 + 1;
    const int pcols = col1 - col0 + 1;
    const int psize = prows * pcols;
    const int wstride = W - pcols;                 // row jump in global plane
    const float inv_pcols = 1.0f / (float)pcols;

    // ---- per-lane DMA source offsets (loop-invariant, byte offsets) ----
    // slot s = k*256 + tid of the interleaved slab; elem e = s>>2, ch = s&3.
    // Global offset from fch (patch-linear -> global via +row*wstride).
    const int smax = (psize + 63) >> 6;            // = ceil(4*psize/256) <= 14
    int gsrc[15];
#pragma unroll
    for (int k = 0; k < 15; ++k) {
        const int sl = k * 256 + tid;
        const int sc = min(sl, 4 * psize - 1);
        const int e  = sc >> 2;
        const int cl = sc & 3;
        const int rr = (int)floorf(((float)e + 0.5f) * inv_pcols);
        gsrc[k] = (cl * HW + e + rr * wstride) * 4;
    }

    // ---- per-lane tap descriptors: sample q of bin -> 4 bilinear taps ----
    int   offs[4];
    float wts[4];
    {
        const int bb = active ? bin : 0;
        const int ph = bb / 7;
        const int pw = bb - ph * 7;
        const int iy = q >> 1, ix = q & 1;
        const float gy = (float)ph + ((float)iy + 0.5f) * 0.5f;
        const float gx = (float)pw + ((float)ix + 0.5f) * 0.5f;
        const float y = y1 + gy * bin_h;
        const float x = x1 + gx * bin_w;
        const bool valid = (y >= -1.0f) && (y <= (float)H) &&
                           (x >= -1.0f) && (x <= (float)W);
        const float yc = fminf(fmaxf(y, 0.0f), (float)(H - 1));
        const float xc = fminf(fmaxf(x, 0.0f), (float)(W - 1));
        const int yl = (int)floorf(yc);
        const int xl = (int)floorf(xc);
        const int yh = min(yl + 1, H - 1);
        const int xh = min(xl + 1, W - 1);
        const float ly = yc - (float)yl;
        const float lx = xc - (float)xl;
        const float hy = 1.0f - ly, hx = 1.0f - lx;
        const float m = valid ? 0.25f : 0.0f;
        const int ry0 = (yl - row0) * pcols, ry1 = (yh - row0) * pcols;
        const int cx0 = xl - col0, cx1 = xh - col0;
        offs[0] = ry0 + cx0;  wts[0] = hy * hx * m;
        offs[1] = ry0 + cx1;  wts[1] = hy * lx * m;
        offs[2] = ry1 + cx0;  wts[2] = ly * hx * m;
        offs[3] = ry1 + cx1;  wts[3] = ly * lx * m;
    }

    // ---- double-buffered interleaved slabs: lds4[s][e] = {c0..c3}[e] ----
    __shared__ float4 lds4[2][SLABQ];    // 30720 B -> 5 blocks/CU

    const int cbase = chunk * CH;
    const float* __restrict__ fch =
        feat + (size_t)(b * C + cbase) * HW + (row0 * W + col0);
    float* __restrict__ outp =
        out + (size_t)r * C * PHW + (size_t)cbase * PHW;

    const int wbase4 = (tid & 192) * 4;  // wave LDS byte base within a batch

    // DMA: dest = wave-uniform base + lane*4 (linear); per-lane global src.
    // smax branch is block-uniform scalar -> no divergence, no collapse.
#define STAGE(SL, CC)                                                      \
    do {                                                                   \
        const char* gb = (const char*)fch + (size_t)(CC) * HW * 4;         \
        char* lb = (char*)(&lds4[SL][0]);                                  \
        _Pragma("unroll")                                                  \
        for (int k = 0; k < 15; ++k) {                                     \
            if (k < smax) {                                                \
                __builtin_amdgcn_global_load_lds(                          \
                    (const __attribute__((address_space(1))) void*)        \
                        (gb + gsrc[k]),                                    \
                    (__attribute__((address_space(3))) void*)              \
                        (lb + k * 1024 + wbase4),                          \
                    4, 0, 0);                                              \
            }                                                              \
        }                                                                  \
    } while (0)

#define COMPUTE(SL, CCV)                                                   \
    do {                                                                   \
        if (active) {                                                      \
            float4 a = make_float4(0.0f, 0.0f, 0.0f, 0.0f);                \
            _Pragma("unroll")                                              \
            for (int j = 0; j < 4; ++j) {                                  \
                const float4 v = lds4[SL][offs[j]];                        \
                a.x += wts[j] * v.x;                                       \
                a.y += wts[j] * v.y;                                       \
                a.z += wts[j] * v.z;                                       \
                a.w += wts[j] * v.w;                                       \
            }                                                              \
            a.x += __shfl_xor(a.x, 1); a.y += __shfl_xor(a.y, 1);          \
            a.z += __shfl_xor(a.z, 1); a.w += __shfl_xor(a.w, 1);          \
            a.x += __shfl_xor(a.x, 2); a.y += __shfl_xor(a.y, 2);          \
            a.z += __shfl_xor(a.z, 2); a.w += __shfl_xor(a.w, 2);          \
            const float vout = (q == 0) ? a.x : (q == 1) ? a.y             \
                             : (q == 2) ? a.z : a.w;                       \
            outp[(size_t)((CCV) + q) * PHW + bin] = vout;                  \
        }                                                                  \
    } while (0)

    // Prologue: DMA slab0 (channels 0..3), drain, publish.
    STAGE(0, 0);
    __syncthreads();                     // vmcnt(0)+lgkmcnt(0)+barrier

    // Segment i: issue DMA for slab nxt (overlaps compute), compute cur,
    // drain + barrier. WAR safe: slab nxt was read at segment i-1; all
    // reads retired (data-dep + lgkm drain) before barrier(i-1), and
    // STAGE(i) issues only after barrier(i-1).
#pragma unroll
    for (int i = 0; i < 8; ++i) {
        const int cur = i & 1;
        if (i < 7) STAGE(cur ^ 1, (i + 1) * 4);
        COMPUTE(cur, i * 4);
        __syncthreads();                 // drains this segment's DMA too
    }
#undef STAGE
#undef COMPUTE
}

extern "C" void kernel_launch(void* const* d_in, const int* in_sizes, int n_in,
                              void* d_out, int out_size, void* d_ws, size_t ws_size,
                              hipStream_t stream) {
    const float* f0 = (const float*)d_in[0];
    const float* f1 = (const float*)d_in[1];
    const float* f2 = (const float*)d_in[2];
    const float* f3 = (const float*)d_in[3];
    const float* boxes = (const float*)d_in[4];
    float* out = (float*)d_out;

    const int R = in_sizes[4] / 4;   // 512 rois
    dim3 grid(R, NCHUNK);
    msroi_kernel<<<grid, 256, 0, stream>>>(f0, f1, f2, f3, boxes, out);
}